// Round 6
// baseline (799.254 us; speedup 1.0000x reference)
//
#include <hip/hip_runtime.h>

#define NN 64
#define NI 6
#define TT 1024
#define BB 1024
#define TB (TT * BB)
#define NSCALE 0.13416407864998738f        // sqrt(2/alpha) * sigma
#define ARNSCALE 0.013416407864998739f     // alpha * NSCALE

// LDS-only barrier: no vmcnt drain, global prefetches stay in flight (round-5 win).
#define BARRIER() do {                                                        \
    __builtin_amdgcn_sched_barrier(0);                                        \
    asm volatile("s_waitcnt lgkmcnt(0)\n\ts_barrier" ::: "memory");           \
    __builtin_amdgcn_sched_barrier(0);                                        \
} while (0)

__device__ __forceinline__ float rdlane(float v, int l) {
    return __int_as_float(__builtin_amdgcn_readlane(__float_as_int(v), l));
}

// 256 blocks x 256 threads. COMPUTE role: wave = batch, lane = neuron -> x-exchange
// via readlane (zero LDS), W_rec row in 64 VGPRs. STAGING/STORE role: thread =
// (n=tid>>2, b=tid&3) -> coalesced 16B-granule VMEM; rn/u/inn and the states store
// pass through tiny double-buffered LDS transposes (~1.3 KB/step/CU total).
__global__ __launch_bounds__(256, 1) void latent_rnn(
    const float* __restrict__ u,      // (6, T, B)
    const float* __restrict__ rn,     // (64, T, B)
    const float* __restrict__ inn,    // (6, T, B)
    const float* __restrict__ Winp,   // (64, 6)
    const float* __restrict__ Wrec,   // (64, 64)
    float* __restrict__ states)       // (64, T, B)
{
    // XCD swizzle: 128 consecutive batches per XCD
    const int hw  = blockIdx.x;
    const int lb  = (hw & 7) * 32 + (hw >> 3);
    const int b0  = lb * 4;
    const int tid = threadIdx.x;
    const int l   = tid & 63;   // compute: lane = neuron
    const int w   = tid >> 6;   // compute: wave = batch b0+w
    const int n   = tid >> 2;   // staging/store: neuron
    const int bs  = tid & 3;    // staging/store: batch b0+bs

    __shared__ float rnT[2][4][NN];   // [parity][batch][neuron]
    __shared__ float iT[2][4][8];     // [parity][batch][input(6)+pad]
    __shared__ float xT[2][4][NN];    // [parity][batch][neuron] (store transpose)

    // ---- per-lane weights (global-sourced; stays in VGPRs — round-2 evidence) ----
    float wreg[NN];
#pragma unroll
    for (int k = 0; k < NN; k += 4) {
        const float4 w4 = *reinterpret_cast<const float4*>(Wrec + l * NN + k);
        wreg[k] = w4.x; wreg[k + 1] = w4.y; wreg[k + 2] = w4.z; wreg[k + 3] = w4.w;
    }
    float wi[NI];
#pragma unroll
    for (int i = 0; i < NI; ++i) wi[i] = Winp[l * NI + i];

    // staging pointers (coalesced: consecutive tids -> consecutive b)
    const float* rsrc = rn + n * TB + b0 + bs;
    float*       sdst = states + n * TB + b0 + bs;
    const bool  ist  = (tid < NI * 4);
    const int   ii   = tid >> 2;          // input index (0..5) when ist
    const int   ib   = tid & 3;
    const float* usrc = u   + ii * TB + b0 + ib;
    const float* isrc = inn + ii * TB + b0 + ib;

    // ---- pre-loop: step-0 data into buf 0; xT[0] = 0; slots hold steps 1..4 ----
    rnT[0][bs][n] = rsrc[0];
    if (ist) iT[0][ib][ii] = fmaf(NSCALE, isrc[0], usrc[0]);
    xT[0][w][l] = 0.0f;

    float rnPF[4], uPF[4], iPF[4];
#pragma unroll
    for (int d = 0; d < 4; ++d) {
        rnPF[d] = rsrc[(d + 1) * BB];
        if (ist) { uPF[d] = usrc[(d + 1) * BB]; iPF[d] = isrc[(d + 1) * BB]; }
    }
    __syncthreads();

    float xreg = 0.0f;

#define STEP(tcur, slot, CC)                                                  \
  {                                                                           \
    /* store states row tcur from last step's transpose (lag-1) */            \
    sdst[(tcur) * BB] = xT[CC][bs][n];                                        \
    /* compute step tcur */                                                   \
    const float rcur = rnT[CC][w][l];                                         \
    const float4 iv0 = *reinterpret_cast<const float4*>(&iT[CC][w][0]);       \
    const float2 iv1 = *reinterpret_cast<const float2*>(&iT[CC][w][4]);       \
    float a0 = 0.f, a1 = 0.f, a2 = 0.f, a3 = 0.f;                             \
    _Pragma("unroll")                                                         \
    for (int k = 0; k < NN; k += 4) {                                         \
        a0 = fmaf(rdlane(xreg, k + 0), wreg[k + 0], a0);                      \
        a1 = fmaf(rdlane(xreg, k + 1), wreg[k + 1], a1);                      \
        a2 = fmaf(rdlane(xreg, k + 2), wreg[k + 2], a2);                      \
        a3 = fmaf(rdlane(xreg, k + 3), wreg[k + 3], a3);                      \
    }                                                                         \
    a0 = fmaf(iv0.x, wi[0], a0); a1 = fmaf(iv0.y, wi[1], a1);                 \
    a2 = fmaf(iv0.z, wi[2], a2); a3 = fmaf(iv0.w, wi[3], a3);                 \
    a0 = fmaf(iv1.x, wi[4], a0); a1 = fmaf(iv1.y, wi[5], a1);                 \
    const float pre = (a0 + a1) + (a2 + a3);                                  \
    const float xn  = fmaf(0.9f, xreg,                                        \
                           fmaf(0.1f, fmaxf(pre, 0.f), ARNSCALE * rcur));     \
    xreg = xn;                                                                \
    /* write next-parity buffers */                                           \
    xT[(CC) ^ 1][w][l] = xn;                                                  \
    rnT[(CC) ^ 1][bs][n] = rnPF[slot];                                        \
    if (ist) iT[(CC) ^ 1][ib][ii] = fmaf(NSCALE, iPF[slot], uPF[slot]);       \
    /* refill slot with step tcur+5 (clamped) */                              \
    { int tp = (tcur) + 5; if (tp > TT - 2) tp = TT - 2;                      \
      rnPF[slot] = rsrc[tp * BB];                                             \
      if (ist) { uPF[slot] = usrc[tp * BB]; iPF[slot] = isrc[tp * BB]; } }    \
    BARRIER();                                                                \
  }

#pragma unroll 1
    for (int t = 0; t < 1020; t += 4) {   // iterations t = 0..1022 compute x[t+1]
        STEP(t + 0, 0, 0);
        STEP(t + 1, 1, 1);
        STEP(t + 2, 2, 0);
        STEP(t + 3, 3, 1);
    }
    STEP(1020, 0, 0);
    STEP(1021, 1, 1);
    STEP(1022, 2, 0);
#undef STEP

    // final row: x[1023] sits in xT[1023&1 = 1]
    sdst[(TT - 1) * BB] = xT[1][bs][n];
}

// outputs = states @ Wout^T : streaming pass (268 MB read, 8 MB write)
__global__ __launch_bounds__(256) void out_proj(
    const float* __restrict__ states,   // (64, T*B)
    const float* __restrict__ Wout,     // (2, 64)
    float* __restrict__ outputs)        // (2, T*B)
{
    const int g4 = (blockIdx.x * 256 + threadIdx.x) * 4;
    float4 a0 = {0.f, 0.f, 0.f, 0.f};
    float4 a1 = {0.f, 0.f, 0.f, 0.f};
#pragma unroll
    for (int k = 0; k < NN; ++k) {
        const float4 s = *reinterpret_cast<const float4*>(states + k * TB + g4);
        const float w0 = Wout[k];
        const float w1 = Wout[NN + k];
        a0.x = fmaf(s.x, w0, a0.x); a0.y = fmaf(s.y, w0, a0.y);
        a0.z = fmaf(s.z, w0, a0.z); a0.w = fmaf(s.w, w0, a0.w);
        a1.x = fmaf(s.x, w1, a1.x); a1.y = fmaf(s.y, w1, a1.y);
        a1.z = fmaf(s.z, w1, a1.z); a1.w = fmaf(s.w, w1, a1.w);
    }
    *reinterpret_cast<float4*>(outputs + g4)      = a0;
    *reinterpret_cast<float4*>(outputs + TB + g4) = a1;
}

extern "C" void kernel_launch(void* const* d_in, const int* in_sizes, int n_in,
                              void* d_out, int out_size, void* d_ws, size_t ws_size,
                              hipStream_t stream) {
    const float* u    = (const float*)d_in[0];
    const float* rn   = (const float*)d_in[1];
    const float* inn  = (const float*)d_in[2];
    const float* Winp = (const float*)d_in[3];
    const float* Wrec = (const float*)d_in[4];
    const float* Wout = (const float*)d_in[5];

    float* states  = (float*)d_out;                          // 64*1024*1024
    float* outputs = (float*)d_out + (size_t)NN * TT * BB;   // 2*1024*1024

    latent_rnn<<<256, 256, 0, stream>>>(u, rn, inn, Winp, Wrec, states);
    out_proj<<<1024, 256, 0, stream>>>(states, Wout, outputs);
}